// Round 5
// baseline (155.253 us; speedup 1.0000x reference)
//
#include <hip/hip_runtime.h>
#include <float.h>
#include <math.h>

#define NREF 100
#define DIM 256
#define K 5
#define ROWS 16        // x rows per block (R=2 per thread, ty 0..7)
#define BLOCK 128
#define W 68           // LDS row stride (64 + 4 pad): stride-W rows => 2-way banks max
#define REF_OFF (ROWS * W)          // 1088 dw
#define NREFP 128
#define LDS_DW (REF_OFF + NREFP * W)  // 9792 dw = 39168 B -> 4 blocks/CU

__global__ __launch_bounds__(BLOCK, 2) void knn_kernel(
    const float* __restrict__ x, const float* __restrict__ ref,
    int* __restrict__ out, int nrows) {
#pragma clang fp contract(off)
  __shared__ float lds[LDS_DW];
  const int tid = threadIdx.x;
  const int tx = tid & 15;   // refs: tx + 16*rr  (rr = 0..7) -> strided, 2-way banks
  const int ty = tid >> 4;   // rows: 2*ty, 2*ty+1
  const int RB = blockIdx.x * ROWS;

  // numpy pairwise state: accumulator q sums d === q (mod 8), t ascending.
  float acc[8][2][8];
  float part[2][8];
#pragma unroll
  for (int q = 0; q < 8; q++)
#pragma unroll
    for (int i = 0; i < 2; i++)
#pragma unroll
      for (int rr = 0; rr < 8; rr++) acc[q][i][rr] = 0.f;

  const float* xb = &lds[2 * ty * W];
  const float* rb = &lds[REF_OFF + tx * W];

#pragma unroll 1
  for (int c = 0; c < 4; c++) {  // 4 x 64-d chunks; numpy 128-block = 2 chunks
    const int DB = c * 64;
    if (c) __syncthreads();  // previous chunk fully consumed
    // ---- stage x: 16 rows x 64 d (256 float4; 2/thread) ----
#pragma unroll
    for (int k = 0; k < 2; k++) {
      const int idx = tid + k * BLOCK;
      const int row = idx >> 4, dp = (idx & 15) << 2;
      const float4 v = *reinterpret_cast<const float4*>(
          x + (size_t)(RB + row) * DIM + DB + dp);
      *reinterpret_cast<float4*>(&lds[row * W + dp]) = v;
    }
    // ---- stage refs: 100 rows x 64 d (pad rows 100..127 stale; never scanned) ----
#pragma unroll
    for (int k = 0; k < 13; k++) {
      const int idx = tid + k * BLOCK;
      const int r = idx >> 4, dp = (idx & 15) << 2;
      if (r < NREF) {
        const float4 v = *reinterpret_cast<const float4*>(
            ref + (size_t)r * DIM + DB + dp);
        *reinterpret_cast<float4*>(&lds[REF_OFF + r * W + dp]) = v;
      }
    }
    __syncthreads();
    // ---- compute: per tt, quad A (d0..d0+3 -> acc 0..3), quad B (+4 -> acc 4..7)
#pragma unroll 2
    for (int tt = 0; tt < 8; tt++) {
      const int d0 = tt << 3;
      {  // quad A
        float4 xv[2], rv[8];
#pragma unroll
        for (int i = 0; i < 2; i++)
          xv[i] = *reinterpret_cast<const float4*>(xb + i * W + d0);
#pragma unroll
        for (int rr = 0; rr < 8; rr++)
          rv[rr] = *reinterpret_cast<const float4*>(rb + rr * 16 * W + d0);
#pragma unroll
        for (int i = 0; i < 2; i++)
#pragma unroll
          for (int rr = 0; rr < 8; rr++) {
            float t0 = xv[i].x - rv[rr].x; float s0 = t0 * t0; acc[0][i][rr] = acc[0][i][rr] + s0;
            float t1 = xv[i].y - rv[rr].y; float s1 = t1 * t1; acc[1][i][rr] = acc[1][i][rr] + s1;
            float t2 = xv[i].z - rv[rr].z; float s2 = t2 * t2; acc[2][i][rr] = acc[2][i][rr] + s2;
            float t3 = xv[i].w - rv[rr].w; float s3 = t3 * t3; acc[3][i][rr] = acc[3][i][rr] + s3;
          }
      }
      {  // quad B
        float4 xv[2], rv[8];
#pragma unroll
        for (int i = 0; i < 2; i++)
          xv[i] = *reinterpret_cast<const float4*>(xb + i * W + d0 + 4);
#pragma unroll
        for (int rr = 0; rr < 8; rr++)
          rv[rr] = *reinterpret_cast<const float4*>(rb + rr * 16 * W + d0 + 4);
#pragma unroll
        for (int i = 0; i < 2; i++)
#pragma unroll
          for (int rr = 0; rr < 8; rr++) {
            float t0 = xv[i].x - rv[rr].x; float s0 = t0 * t0; acc[4][i][rr] = acc[4][i][rr] + s0;
            float t1 = xv[i].y - rv[rr].y; float s1 = t1 * t1; acc[5][i][rr] = acc[5][i][rr] + s1;
            float t2 = xv[i].z - rv[rr].z; float s2 = t2 * t2; acc[6][i][rr] = acc[6][i][rr] + s2;
            float t3 = xv[i].w - rv[rr].w; float s3 = t3 * t3; acc[7][i][rr] = acc[7][i][rr] + s3;
          }
      }
    }
    // ---- end of 128-d numpy block: exact tree fold ----
    if (c & 1) {
#pragma unroll
      for (int i = 0; i < 2; i++)
#pragma unroll
        for (int rr = 0; rr < 8; rr++) {
          const float s03 = (acc[0][i][rr] + acc[1][i][rr]) + (acc[2][i][rr] + acc[3][i][rr]);
          const float s47 = (acc[4][i][rr] + acc[5][i][rr]) + (acc[6][i][rr] + acc[7][i][rr]);
          const float blk = s03 + s47;
          part[i][rr] = (c == 1) ? blk : (part[i][rr] + blk);  // total = L + R
#pragma unroll
          for (int q = 0; q < 8; q++) acc[q][i][rr] = 0.f;
        }
    }
  }
  __syncthreads();  // staging dead; reuse LDS for keys [16][132]
#pragma unroll
  for (int i = 0; i < 2; i++)
#pragma unroll
    for (int rr = 0; rr < 8; rr++)
      lds[(2 * ty + i) * 132 + tx + 16 * rr] = sqrtf(part[i][rr]);
  __syncthreads();
  // ---- top-5: strict < insertion => lowest index wins ties (lax.top_k) ----
  if (tid < ROWS) {
    float best[K]; int bidx[K];
#pragma unroll
    for (int k = 0; k < K; k++) { best[k] = FLT_MAX; bidx[k] = 0; }
    for (int r = 0; r < NREF; r++) {
      const float kv = lds[tid * 132 + r];
      if (kv < best[K - 1]) {
        int pos = K - 1;
        while (pos > 0 && kv < best[pos - 1]) {
          best[pos] = best[pos - 1]; bidx[pos] = bidx[pos - 1]; pos--;
        }
        best[pos] = kv; bidx[pos] = r;
      }
    }
    int* o = out + (size_t)(RB + tid) * K;
#pragma unroll
    for (int k = 0; k < K; k++) o[k] = bidx[k];
  }
}

extern "C" void kernel_launch(void* const* d_in, const int* in_sizes, int n_in,
                              void* d_out, int out_size, void* d_ws, size_t ws_size,
                              hipStream_t stream) {
  const float* x = (const float*)d_in[0];
  const float* ref = (const float*)d_in[1];
  int* out = (int*)d_out;
  const int nrows = in_sizes[0] / DIM;  // 16384
  const int grid = (nrows + ROWS - 1) / ROWS;  // 1024
  knn_kernel<<<grid, BLOCK, 0, stream>>>(x, ref, out, nrows);
}

// Round 6
// 148.704 us; speedup vs baseline: 1.0440x; 1.0440x over previous
//
#include <hip/hip_runtime.h>
#include <float.h>
#include <math.h>

#define NREF 100
#define DIM 256
#define K 5
#define ROWS 32        // rows per block (R=4 per thread, ty 0..7)
#define BLOCK 256
#define W 68           // LDS row stride (64 + 4 pad)
#define REF_OFF (ROWS * W)            // 2176 dw
#define NREFP 128
#define LDS_DW (REF_OFF + NREFP * W)  // 10880 dw = 43520 B

__global__ __launch_bounds__(BLOCK, 2) void knn_kernel(
    const float* __restrict__ x, const float* __restrict__ ref,
    int* __restrict__ out, int nrows) {
#pragma clang fp contract(off)
  __shared__ float lds[LDS_DW];
  const int tid = threadIdx.x;
  const int tx = tid & 31;   // refs: tx + 32*rr (rr = 0..3)
  const int ty = tid >> 5;   // rows: 4*ty .. 4*ty+3
  const int RB = blockIdx.x * ROWS;

  // numpy pairwise state: accumulator q sums d === q (mod 8), t ascending.
  float acc[8][4][4];
  float part[4][4];
#pragma unroll
  for (int q = 0; q < 8; q++)
#pragma unroll
    for (int i = 0; i < 4; i++)
#pragma unroll
      for (int rr = 0; rr < 4; rr++) acc[q][i][rr] = 0.f;

  const float* xb = &lds[4 * ty * W];
  const float* rb = &lds[REF_OFF + tx * W];

#pragma unroll 1
  for (int c = 0; c < 4; c++) {  // 4 x 64-d chunks; numpy 128-block = 2 chunks
    const int DB = c * 64;
    if (c) __syncthreads();  // previous chunk fully consumed
    // ---- stage x: 32 rows x 64 d (512 float4; 2/thread) ----
#pragma unroll
    for (int k = 0; k < 2; k++) {
      const int idx = tid + k * BLOCK;
      const int row = idx >> 4, dp = (idx & 15) << 2;
      const float4 v = *reinterpret_cast<const float4*>(
          x + (size_t)(RB + row) * DIM + DB + dp);
      *reinterpret_cast<float4*>(&lds[row * W + dp]) = v;
    }
    // ---- stage refs: 100 rows x 64 d (pad rows stale; keys never scanned) ----
#pragma unroll
    for (int k = 0; k < 7; k++) {
      const int idx = tid + k * BLOCK;
      const int r = idx >> 4, dp = (idx & 15) << 2;
      if (r < NREF) {
        const float4 v = *reinterpret_cast<const float4*>(
            ref + (size_t)r * DIM + DB + dp);
        *reinterpret_cast<float4*>(&lds[REF_OFF + r * W + dp]) = v;
      }
    }
    __syncthreads();
    // ---- compute: per tt, quad A (d0+0..3 -> acc 0..3), quad B (+4 -> acc 4..7)
#pragma unroll 2
    for (int tt = 0; tt < 8; tt++) {
      const int d0 = tt << 3;
      {  // quad A
        float4 xv[4], rv[4];
#pragma unroll
        for (int i = 0; i < 4; i++)
          xv[i] = *reinterpret_cast<const float4*>(xb + i * W + d0);
#pragma unroll
        for (int rr = 0; rr < 4; rr++)
          rv[rr] = *reinterpret_cast<const float4*>(rb + rr * 32 * W + d0);
#pragma unroll
        for (int i = 0; i < 4; i++)
#pragma unroll
          for (int rr = 0; rr < 4; rr++) {
            float t0 = xv[i].x - rv[rr].x; float s0 = t0 * t0; acc[0][i][rr] = acc[0][i][rr] + s0;
            float t1 = xv[i].y - rv[rr].y; float s1 = t1 * t1; acc[1][i][rr] = acc[1][i][rr] + s1;
            float t2 = xv[i].z - rv[rr].z; float s2 = t2 * t2; acc[2][i][rr] = acc[2][i][rr] + s2;
            float t3 = xv[i].w - rv[rr].w; float s3 = t3 * t3; acc[3][i][rr] = acc[3][i][rr] + s3;
          }
      }
      {  // quad B
        float4 xv[4], rv[4];
#pragma unroll
        for (int i = 0; i < 4; i++)
          xv[i] = *reinterpret_cast<const float4*>(xb + i * W + d0 + 4);
#pragma unroll
        for (int rr = 0; rr < 4; rr++)
          rv[rr] = *reinterpret_cast<const float4*>(rb + rr * 32 * W + d0 + 4);
#pragma unroll
        for (int i = 0; i < 4; i++)
#pragma unroll
          for (int rr = 0; rr < 4; rr++) {
            float t0 = xv[i].x - rv[rr].x; float s0 = t0 * t0; acc[4][i][rr] = acc[4][i][rr] + s0;
            float t1 = xv[i].y - rv[rr].y; float s1 = t1 * t1; acc[5][i][rr] = acc[5][i][rr] + s1;
            float t2 = xv[i].z - rv[rr].z; float s2 = t2 * t2; acc[6][i][rr] = acc[6][i][rr] + s2;
            float t3 = xv[i].w - rv[rr].w; float s3 = t3 * t3; acc[7][i][rr] = acc[7][i][rr] + s3;
          }
      }
    }
    // ---- end of 128-d numpy block: exact tree fold ----
    if (c & 1) {
#pragma unroll
      for (int i = 0; i < 4; i++)
#pragma unroll
        for (int rr = 0; rr < 4; rr++) {
          const float s03 = (acc[0][i][rr] + acc[1][i][rr]) + (acc[2][i][rr] + acc[3][i][rr]);
          const float s47 = (acc[4][i][rr] + acc[5][i][rr]) + (acc[6][i][rr] + acc[7][i][rr]);
          const float blk = s03 + s47;
          part[i][rr] = (c == 1) ? blk : (part[i][rr] + blk);  // total = L + R
#pragma unroll
          for (int q = 0; q < 8; q++) acc[q][i][rr] = 0.f;
        }
    }
  }
  __syncthreads();  // staging dead; reuse LDS for keys [32][132]
#pragma unroll
  for (int i = 0; i < 4; i++)
#pragma unroll
    for (int rr = 0; rr < 4; rr++)
      lds[(4 * ty + i) * 132 + tx + 32 * rr] = sqrtf(part[i][rr]);
  __syncthreads();
  // ---- top-5: strict < insertion => lowest index wins ties (lax.top_k) ----
  if (tid < ROWS) {
    float best[K]; int bidx[K];
#pragma unroll
    for (int k = 0; k < K; k++) { best[k] = FLT_MAX; bidx[k] = 0; }
    for (int r = 0; r < NREF; r++) {
      const float kv = lds[tid * 132 + r];
      if (kv < best[K - 1]) {
        int pos = K - 1;
        while (pos > 0 && kv < best[pos - 1]) {
          best[pos] = best[pos - 1]; bidx[pos] = bidx[pos - 1]; pos--;
        }
        best[pos] = kv; bidx[pos] = r;
      }
    }
    int* o = out + (size_t)(RB + tid) * K;
#pragma unroll
    for (int k = 0; k < K; k++) o[k] = bidx[k];
  }
}

extern "C" void kernel_launch(void* const* d_in, const int* in_sizes, int n_in,
                              void* d_out, int out_size, void* d_ws, size_t ws_size,
                              hipStream_t stream) {
  const float* x = (const float*)d_in[0];
  const float* ref = (const float*)d_in[1];
  int* out = (int*)d_out;
  const int nrows = in_sizes[0] / DIM;  // 16384
  const int grid = (nrows + ROWS - 1) / ROWS;  // 512
  knn_kernel<<<grid, BLOCK, 0, stream>>>(x, ref, out, nrows);
}